// Round 2
// baseline (4090.756 us; speedup 1.0000x reference)
//
#include <hip/hip_runtime.h>
#include <hip/hip_bf16.h>

// ---- model dims ----
constexpr int TB = 512, TL = 200, TH = 128, TNH = 4, TD = 32;
constexpr int TFT = 32, TTP = 64, TIP = 200;
constexpr int TSH = 512, TFH = 256;
constexpr int TITEMS = 100001;
constexpr int TNT = TB * TTP;   // 32768
constexpr int TNI = TB * TIP;   // 102400

__device__ inline float gelu_exact(float x) {
    return 0.5f * x * (1.0f + erff(x * 0.7071067811865476f));
}

__device__ inline float block_reduce_sum(float v, float* red) {
    for (int o = 32; o > 0; o >>= 1) v += __shfl_down(v, o, 64);
    int nw = blockDim.x >> 6;
    if ((threadIdx.x & 63) == 0) red[threadIdx.x >> 6] = v;
    __syncthreads();
    float r = 0.f;
    for (int w = 0; w < nw; ++w) r += red[w];
    __syncthreads();
    return r;
}

__device__ inline float block_reduce_max(float v, float* red) {
    for (int o = 32; o > 0; o >>= 1) v = fmaxf(v, __shfl_down(v, o, 64));
    int nw = blockDim.x >> 6;
    if ((threadIdx.x & 63) == 0) red[threadIdx.x >> 6] = v;
    __syncthreads();
    float r = -INFINITY;
    for (int w = 0; w < nw; ++w) r = fmaxf(r, red[w]);
    __syncthreads();
    return r;
}

// out[r,:] = table[idx[r],:]   (H=128 floats per row, float4 vectorized)
__global__ __launch_bounds__(256) void k_gather(const float* __restrict__ tab,
                                                const int* __restrict__ idx,
                                                float* __restrict__ out, int nrows) {
    int e = blockIdx.x * blockDim.x + threadIdx.x;
    if (e >= nrows * 32) return;
    int r = e >> 5, c = e & 31;
    ((float4*)out)[e] = ((const float4*)tab)[(size_t)idx[r] * 32 + c];
}

// row-wise LayerNorm over H=128, eps=1e-8
__global__ __launch_bounds__(128) void k_ln(const float* __restrict__ x, float* __restrict__ y,
                                            const float* __restrict__ g, const float* __restrict__ b) {
    __shared__ float red[2];
    int r = blockIdx.x, t = threadIdx.x;
    float v = x[(size_t)r * TH + t];
    float mean = block_reduce_sum(v, red) * (1.f / TH);
    float d = v - mean;
    float var = block_reduce_sum(d * d, red) * (1.f / TH);
    y[(size_t)r * TH + t] = d * rsqrtf(var + 1e-8f) * g[t] + b[t];
}

// fused seq-mixing block: per (b, group of 8 h):
//   t[s] = gelu(sum_l nv[b,l,h]*w1[l,s]);  vs[b,l,h] = nv[b,l,h] + sum_s t[s]*w2[s,l]
__global__ __launch_bounds__(256) void k_scb(const float* __restrict__ nv, float* __restrict__ vs,
                                             const float* __restrict__ w1, const float* __restrict__ w2) {
    __shared__ float nvc[8][TL];
    __shared__ float tt[8][TSH];
    int b = blockIdx.x >> 4;
    int h0 = (blockIdx.x & 15) * 8;
    int tid = threadIdx.x;
    for (int i = tid; i < 8 * TL; i += 256) {
        int hh = i / TL, l = i % TL;
        nvc[hh][l] = nv[(size_t)(b * TL + l) * TH + h0 + hh];
    }
    __syncthreads();
    for (int s = tid; s < TSH; s += 256) {
        float acc[8];
#pragma unroll
        for (int hh = 0; hh < 8; ++hh) acc[hh] = 0.f;
        for (int l = 0; l < TL; ++l) {
            float w = w1[l * TSH + s];
#pragma unroll
            for (int hh = 0; hh < 8; ++hh) acc[hh] += nvc[hh][l] * w;
        }
#pragma unroll
        for (int hh = 0; hh < 8; ++hh) tt[hh][s] = gelu_exact(acc[hh]);
    }
    __syncthreads();
    for (int l = tid; l < TL; l += 256) {
        float acc[8];
#pragma unroll
        for (int hh = 0; hh < 8; ++hh) acc[hh] = 0.f;
        for (int s = 0; s < TSH; ++s) {
            float w = w2[s * TL + l];
#pragma unroll
            for (int hh = 0; hh < 8; ++hh) acc[hh] += tt[hh][s] * w;
        }
#pragma unroll
        for (int hh = 0; hh < 8; ++hh)
            vs[(size_t)(b * TL + l) * TH + h0 + hh] = nvc[hh][l] + acc[hh];
    }
}

// fused per-(b,l group of 4) feature block:
//  y=gelu(xh@w1); z=y@w2; V = nvs + z@w3
__global__ __launch_bounds__(256) void k_fcb(const float* __restrict__ nvs, float* __restrict__ V,
                                             const float* __restrict__ w1, const float* __restrict__ w2,
                                             const float* __restrict__ w3) {
    __shared__ float xs[4][TH];
    __shared__ float ys[4][1024];
    __shared__ float zs[4][TH];
    int bl0 = blockIdx.x * 4;
    int tid = threadIdx.x;
    for (int i = tid; i < 4 * TH; i += 256) {
        int il = i >> 7, h = i & 127;
        xs[il][h] = nvs[(size_t)(bl0 + il) * TH + h];
    }
    __syncthreads();
    for (int i = tid; i < 4 * 1024; i += 256) {
        int il = i >> 10, kf = i & 1023, k = kf >> 8, f = kf & 255;
        float a = 0.f;
#pragma unroll
        for (int c = 0; c < TD; ++c) a += xs[il][k * TD + c] * w1[c * TFH + f];
        ys[il][kf] = gelu_exact(a);
    }
    __syncthreads();
    for (int i = tid; i < 4 * TH; i += 256) {
        int il = i >> 7, h = i & 127, k = h >> 5, c = h & 31;
        float a = 0.f;
        for (int f = 0; f < TFH; ++f) a += ys[il][k * TFH + f] * w2[f * TD + c];
        zs[il][h] = a;
    }
    __syncthreads();
    for (int i = tid; i < 4 * TH; i += 256) {
        int il = i >> 7, h = i & 127;
        float a = 0.f;
        for (int hp = 0; hp < TH; ++hp) a += zs[il][hp] * w3[hp * TH + h];
        V[(size_t)(bl0 + il) * TH + h] = xs[il][h] + a;
    }
}

// alpha = softmax(V@wv over L); g = sum_l alpha*V
__global__ __launch_bounds__(256) void k_pool(const float* __restrict__ V, const float* __restrict__ wv,
                                              float* __restrict__ g) {
    __shared__ float sc[TL];
    __shared__ float red[4];
    int b = blockIdx.x, tid = threadIdx.x;
    if (tid < TL) {
        float a = 0.f;
        const float* vp = V + (size_t)(b * TL + tid) * TH;
        for (int h = 0; h < TH; ++h) a += vp[h] * wv[h];
        sc[tid] = a;
    }
    __syncthreads();
    float m = (tid < TL) ? sc[tid] : -INFINITY;
    m = block_reduce_max(m, red);
    float e = (tid < TL) ? expf(sc[tid] - m) : 0.f;
    float s = block_reduce_sum(e, red);
    if (tid < TL) sc[tid] = e / s;
    __syncthreads();
    if (tid < TH) {
        float a = 0.f;
        for (int l = 0; l < TL; ++l) a += sc[l] * V[(size_t)(b * TL + l) * TH + tid];
        g[b * TH + tid] = a;
    }
}

// y[N,128] = x[N,128] @ W[128,128]
__global__ __launch_bounds__(256) void k_gemm128(const float* __restrict__ x, const float* __restrict__ W,
                                                 float* __restrict__ y, int nrows) {
    __shared__ float xs[32][TH];
    int row0 = blockIdx.x * 32;
    int tid = threadIdx.x;
    for (int i = tid; i < 32 * TH; i += 256) {
        int r = i >> 7, h = i & 127;
        int rr = row0 + r;
        xs[r][h] = (rr < nrows) ? x[(size_t)rr * TH + h] : 0.f;
    }
    __syncthreads();
    int c = tid & 127, rg = tid >> 7;
    float acc[16];
#pragma unroll
    for (int i = 0; i < 16; ++i) acc[i] = 0.f;
    for (int h = 0; h < TH; ++h) {
        float w = W[h * TH + c];
#pragma unroll
        for (int i = 0; i < 16; ++i) acc[i] += xs[rg + 2 * i][h] * w;
    }
#pragma unroll
    for (int i = 0; i < 16; ++i) {
        int rr = row0 + rg + 2 * i;
        if (rr < nrows) y[(size_t)rr * TH + c] = acc[i];
    }
}

// out[n,k] = sum_d f[n, k*32+d] * vec[k*32+d]
__global__ __launch_bounds__(256) void k_scores(const float* __restrict__ f, const float* __restrict__ vec,
                                                float* __restrict__ out, int n) {
    int idx = blockIdx.x * blockDim.x + threadIdx.x;
    if (idx >= n * TNH) return;
    int node = idx >> 2, k = idx & 3;
    const float* fp = f + (size_t)node * TH + k * TD;
    const float* vp = vec + k * TD;
    float a = 0.f;
#pragma unroll
    for (int d = 0; d < TD; ++d) a += fp[d] * vp[d];
    out[idx] = a;
}

// fused per-dst-node GAT for both graphs; deg_i=4, deg_t=2; writes tax_nxt, acc
__global__ __launch_bounds__(128) void k_gat(const float* __restrict__ tax_cur,
                                             const float* __restrict__ fs_i, const float* __restrict__ el_i,
                                             const float* __restrict__ er_i, const int* __restrict__ src_i,
                                             const float* __restrict__ bi,
                                             const float* __restrict__ fs_t, const float* __restrict__ el_t,
                                             const float* __restrict__ er_t, const int* __restrict__ src_t,
                                             const float* __restrict__ bt,
                                             float* __restrict__ tax_nxt, float* __restrict__ acc, int hop) {
    int n = blockIdx.x, h = threadIdx.x, k = h >> 5;
    float cur = tax_cur[(size_t)n * TH + h];
    float ti, tt2;
    {
        float er = er_i[n * 4 + k];
        int s[4]; float e[4]; float m = -INFINITY;
#pragma unroll
        for (int j = 0; j < 4; ++j) {
            s[j] = src_i[n * 4 + j];
            float xx = el_i[s[j] * 4 + k] + er;
            e[j] = xx > 0.f ? xx : 0.2f * xx;
            m = fmaxf(m, e[j]);
        }
        float ssum = 0.f, av = 0.f;
#pragma unroll
        for (int j = 0; j < 4; ++j) {
            float a = expf(e[j] - m);
            ssum += a;
            av += a * fs_i[(size_t)s[j] * TH + h];
        }
        ti = fmaxf(av / ssum + cur + bi[h], 0.f);
    }
    {
        float er = er_t[n * 4 + k];
        int s[2]; float e[2]; float m = -INFINITY;
#pragma unroll
        for (int j = 0; j < 2; ++j) {
            s[j] = src_t[n * 2 + j];
            float xx = el_t[s[j] * 4 + k] + er;
            e[j] = xx > 0.f ? xx : 0.2f * xx;
            m = fmaxf(m, e[j]);
        }
        float ssum = 0.f, av = 0.f;
#pragma unroll
        for (int j = 0; j < 2; ++j) {
            float a = expf(e[j] - m);
            ssum += a;
            av += a * fs_t[(size_t)s[j] * TH + h];
        }
        tt2 = fmaxf(av / ssum + cur + bt[h], 0.f);
    }
    float nx = ti + tt2;
    size_t ai = (size_t)n * TH + h;
    tax_nxt[ai] = nx;
    acc[ai] = (hop == 0) ? nx : acc[ai] + nx;
}

// local[b,f,:] = valid ? acc[clip(root)+b*TP]/2 : 0 ; mul[b,f] = dot(local, g[b])
__global__ __launch_bounds__(128) void k_local(const int* __restrict__ root, const float* __restrict__ acc,
                                               const float* __restrict__ g, float* __restrict__ local,
                                               float* __restrict__ mul) {
    __shared__ float red[2];
    int bf = blockIdx.x, b = bf >> 5;
    int h = threadIdx.x;
    int r = root[bf];
    float v = 0.f;
    if (r != -1) {
        int rc = r < 0 ? 0 : r;
        v = acc[(size_t)(b * TTP + rc) * TH + h] * 0.5f;
    }
    local[(size_t)bf * TH + h] = v;
    float s = block_reduce_sum(v * g[b * TH + h], red);
    if (h == 0) mul[bf] = s;
}

// per-b: LN(mul) masked softmax -> w; intention = LN(g + sum_f w*local); p = intention @ uni_w
__global__ __launch_bounds__(128) void k_fuse(const float* __restrict__ mul, const float* __restrict__ local,
                                              const float* __restrict__ g,
                                              const float* __restrict__ liw_g, const float* __restrict__ liw_b,
                                              const float* __restrict__ int_g, const float* __restrict__ int_b,
                                              const float* __restrict__ uni_w, float* __restrict__ p) {
    __shared__ float lm[TFT], wv_[TFT], inten[TH];
    __shared__ float red[2];
    int b = blockIdx.x, tid = threadIdx.x;
    if (tid < TFT) lm[tid] = mul[b * TFT + tid];
    __syncthreads();
    if (tid < TFT) {
        float mean = 0.f;
        for (int f = 0; f < TFT; ++f) mean += lm[f];
        mean *= (1.f / TFT);
        float var = 0.f;
        for (int f = 0; f < TFT; ++f) { float d = lm[f] - mean; var += d * d; }
        var *= (1.f / TFT);
        float ln = (lm[tid] - mean) * rsqrtf(var + 1e-8f) * liw_g[tid] + liw_b[tid];
        wv_[tid] = (lm[tid] != 0.f) ? ln : -INFINITY;
    }
    __syncthreads();
    if (tid < TFT) {
        float mx = -INFINITY;
        for (int f = 0; f < TFT; ++f) mx = fmaxf(mx, wv_[f]);
        float s = 0.f;
        for (int f = 0; f < TFT; ++f) s += expf(wv_[f] - mx);
        lm[tid] = expf(wv_[tid] - mx) / s;   // lm now holds w
    }
    __syncthreads();
    float ip = g[b * TH + tid];
    for (int f = 0; f < TFT; ++f) ip += lm[f] * local[(size_t)(b * TFT + f) * TH + tid];
    float mean = block_reduce_sum(ip, red) * (1.f / TH);
    float d = ip - mean;
    float var = block_reduce_sum(d * d, red) * (1.f / TH);
    inten[tid] = d * rsqrtf(var + 1e-8f) * int_g[tid] + int_b[tid];
    __syncthreads();
    float a = 0.f;
    for (int hp = 0; hp < TH; ++hp) a += inten[hp] * uni_w[hp * TH + tid];
    p[b * TH + tid] = a;
}

// out[b,i] = dot(p[b,:], E[i,:]) -> f32 ; 16b x 64i tile per block
__global__ __launch_bounds__(256) void k_final(const float* __restrict__ p, const float* __restrict__ E,
                                               float* __restrict__ out) {
    __shared__ float ps[16][TH];
    __shared__ float es[64][TH + 1];
    int i0 = blockIdx.x * 64, b0 = blockIdx.y * 16;
    int tid = threadIdx.x;
    for (int i = tid; i < 16 * TH; i += 256) {
        int bb = i >> 7, h = i & 127;
        ps[bb][h] = p[(b0 + bb) * TH + h];
    }
    for (int i = tid; i < 64 * TH; i += 256) {
        int ii = i >> 7, h = i & 127;
        int it = i0 + ii;
        es[ii][h] = (it < TITEMS) ? E[(size_t)it * TH + h] : 0.f;
    }
    __syncthreads();
    int ii = tid & 63, bq = tid >> 6;
    float acc[4] = {0.f, 0.f, 0.f, 0.f};
    for (int h = 0; h < TH; ++h) {
        float ev = es[ii][h];
#pragma unroll
        for (int t = 0; t < 4; ++t) acc[t] += ps[bq * 4 + t][h] * ev;
    }
    int it = i0 + ii;
    if (it < TITEMS) {
#pragma unroll
        for (int t = 0; t < 4; ++t)
            out[(size_t)(b0 + bq * 4 + t) * TITEMS + it] = acc[t];
    }
}

extern "C" void kernel_launch(void* const* d_in, const int* in_sizes, int n_in,
                              void* d_out, int out_size, void* d_ws, size_t ws_size,
                              hipStream_t stream) {
    const int*   seq        = (const int*)d_in[0];
    const int*   root       = (const int*)d_in[1];
    const int*   i2t_src    = (const int*)d_in[3];
    const int*   t2t_src    = (const int*)d_in[5];
    const int*   item_ids   = (const int*)d_in[6];
    const int*   tax_ids    = (const int*)d_in[7];
    const float* item_embed = (const float*)d_in[8];
    const float* tax_embed  = (const float*)d_in[9];
    const float* scb_ln_g   = (const float*)d_in[10];
    const float* scb_ln_b   = (const float*)d_in[11];
    const float* scb_w1     = (const float*)d_in[12];
    const float* scb_w2     = (const float*)d_in[13];
    const float* fcb_ln_g   = (const float*)d_in[14];
    const float* fcb_ln_b   = (const float*)d_in[15];
    const float* fcb_w1     = (const float*)d_in[16];
    const float* fcb_w2     = (const float*)d_in[17];
    const float* fcb_w3     = (const float*)d_in[18];
    const float* wv         = (const float*)d_in[19];
    const float* gi_w       = (const float*)d_in[20];
    const float* gi_al      = (const float*)d_in[21];
    const float* gi_ar      = (const float*)d_in[22];
    const float* gi_b       = (const float*)d_in[23];
    const float* gt_w       = (const float*)d_in[24];
    const float* gt_al      = (const float*)d_in[25];
    const float* gt_ar      = (const float*)d_in[26];
    const float* gt_b       = (const float*)d_in[27];
    const float* liw_g      = (const float*)d_in[28];
    const float* liw_b      = (const float*)d_in[29];
    const float* int_g      = (const float*)d_in[30];
    const float* int_b      = (const float*)d_in[31];
    const float* uni_w      = (const float*)d_in[32];

    char* w = (char*)d_ws;
    float* V     = (float*)(w + 0);           // 52,428,800 B (region A: V / fs_i)
    float* NV    = (float*)(w + 52428800);    // 52,428,800 B (region B: nv / item_h)
    float* FSI   = V;
    float* ITEMH = NV;
    float* TAX0  = (float*)(w + 104857600);   // 16,777,216
    float* TAX1  = (float*)(w + 121634816);   // 16,777,216
    float* ACC   = (float*)(w + 138412032);   // 16,777,216
    float* FDI   = (float*)(w + 155189248);   // 16,777,216
    float* FST   = (float*)(w + 171966464);   // 16,777,216
    float* ELI   = (float*)(w + 188743680);   // 1,638,400
    float* ERI   = (float*)(w + 190382080);   // 524,288
    float* ELT   = (float*)(w + 190906368);   // 524,288
    float* ERT   = (float*)(w + 191430656);   // 524,288
    float* LOCAL = (float*)(w + 191954944);   // 8,388,608
    float* G     = (float*)(w + 200343552);   // 262,144
    float* MUL   = (float*)(w + 200605696);   // 65,536
    float* P     = (float*)(w + 200671232);   // 262,144
    if (ws_size < 200933376ull) return;

    // ---- global intention (mixer) ----
    k_gather<<<(TB * TL * 32 + 255) / 256, 256, 0, stream>>>(item_embed, seq, V, TB * TL);
    for (int nb = 0; nb < 2; ++nb) {
        k_ln<<<TB * TL, 128, 0, stream>>>(V, NV, scb_ln_g + nb * TH, scb_ln_b + nb * TH);
        k_scb<<<TB * 16, 256, 0, stream>>>(NV, V, scb_w1 + nb * TL * TSH, scb_w2 + nb * TSH * TL);
        k_ln<<<TB * TL, 128, 0, stream>>>(V, NV, fcb_ln_g + nb * TH, fcb_ln_b + nb * TH);
        k_fcb<<<TB * TL / 4, 256, 0, stream>>>(NV, V, fcb_w1 + nb * TD * TFH,
                                               fcb_w2 + nb * TFH * TD, fcb_w3 + nb * TH * TH);
    }
    k_pool<<<TB, 256, 0, stream>>>(V, wv, G);

    // ---- local intention (GAT) ----
    k_gather<<<(TNI * 32 + 255) / 256, 256, 0, stream>>>(item_embed, item_ids, ITEMH, TNI);
    k_gather<<<(TNT * 32 + 255) / 256, 256, 0, stream>>>(tax_embed, tax_ids, TAX0, TNT);

    float* cur = TAX0;
    float* nxt = TAX1;
    for (int hop = 0; hop < 2; ++hop) {
        const float* Wi = gi_w + hop * TH * TH;
        const float* Wt = gt_w + hop * TH * TH;
        k_gemm128<<<(TNI + 31) / 32, 256, 0, stream>>>(ITEMH, Wi, FSI, TNI);
        k_gemm128<<<(TNT + 31) / 32, 256, 0, stream>>>(cur, Wi, FDI, TNT);
        k_gemm128<<<(TNT + 31) / 32, 256, 0, stream>>>(cur, Wt, FST, TNT);
        k_scores<<<(TNI * TNH + 255) / 256, 256, 0, stream>>>(FSI, gi_al + hop * TH, ELI, TNI);
        k_scores<<<(TNT * TNH + 255) / 256, 256, 0, stream>>>(FDI, gi_ar + hop * TH, ERI, TNT);
        k_scores<<<(TNT * TNH + 255) / 256, 256, 0, stream>>>(FST, gt_al + hop * TH, ELT, TNT);
        k_scores<<<(TNT * TNH + 255) / 256, 256, 0, stream>>>(FST, gt_ar + hop * TH, ERT, TNT);
        k_gat<<<TNT, 128, 0, stream>>>(cur, FSI, ELI, ERI, i2t_src, gi_b + hop * TH,
                                       FST, ELT, ERT, t2t_src, gt_b + hop * TH, nxt, ACC, hop);
        float* tmp = cur; cur = nxt; nxt = tmp;
    }

    // ---- fuse ----
    k_local<<<TB * TFT, 128, 0, stream>>>(root, ACC, G, LOCAL, MUL);
    k_fuse<<<TB, 128, 0, stream>>>(MUL, LOCAL, G, liw_g, liw_b, int_g, int_b, uni_w, P);

    dim3 fgrid((TITEMS + 63) / 64, TB / 16);
    k_final<<<fgrid, 256, 0, stream>>>(P, item_embed, (float*)d_out);
}

// Round 3
// 2905.865 us; speedup vs baseline: 1.4078x; 1.4078x over previous
//
#include <hip/hip_runtime.h>
#include <hip/hip_bf16.h>

// ---- model dims ----
constexpr int TB = 512, TL = 200, TH = 128, TNH = 4, TD = 32;
constexpr int TFT = 32, TTP = 64, TIP = 200;
constexpr int TSH = 512, TFH = 256;
constexpr int TITEMS = 100001;
constexpr int TNT = TB * TTP;   // 32768
constexpr int TNI = TB * TIP;   // 102400

__device__ inline float gelu_exact(float x) {
    return 0.5f * x * (1.0f + erff(x * 0.7071067811865476f));
}

__device__ inline float block_reduce_sum(float v, float* red) {
    for (int o = 32; o > 0; o >>= 1) v += __shfl_down(v, o, 64);
    int nw = blockDim.x >> 6;
    if ((threadIdx.x & 63) == 0) red[threadIdx.x >> 6] = v;
    __syncthreads();
    float r = 0.f;
    for (int w = 0; w < nw; ++w) r += red[w];
    __syncthreads();
    return r;
}

__device__ inline float block_reduce_max(float v, float* red) {
    for (int o = 32; o > 0; o >>= 1) v = fmaxf(v, __shfl_down(v, o, 64));
    int nw = blockDim.x >> 6;
    if ((threadIdx.x & 63) == 0) red[threadIdx.x >> 6] = v;
    __syncthreads();
    float r = -INFINITY;
    for (int w = 0; w < nw; ++w) r = fmaxf(r, red[w]);
    __syncthreads();
    return r;
}

// out[r,:] = table[idx[r],:]
__global__ __launch_bounds__(256) void k_gather(const float* __restrict__ tab,
                                                const int* __restrict__ idx,
                                                float* __restrict__ out, int nrows) {
    int e = blockIdx.x * blockDim.x + threadIdx.x;
    if (e >= nrows * 32) return;
    int r = e >> 5, c = e & 31;
    ((float4*)out)[e] = ((const float4*)tab)[(size_t)idx[r] * 32 + c];
}

// row-wise LayerNorm over H=128: 8 rows / 256-thread block, float4 lanes
__global__ __launch_bounds__(256) void k_ln(const float* __restrict__ x, float* __restrict__ y,
                                            const float* __restrict__ g, const float* __restrict__ b) {
    int row = blockIdx.x * 8 + (threadIdx.x >> 5);
    int lane = threadIdx.x & 31;
    const float4 v = ((const float4*)(x + (size_t)row * TH))[lane];
    float s = v.x + v.y + v.z + v.w;
    for (int o = 16; o > 0; o >>= 1) s += __shfl_down(s, o, 32);
    float mean = __shfl(s, 0, 32) * (1.f / 128.f);
    float4 d;
    d.x = v.x - mean; d.y = v.y - mean; d.z = v.z - mean; d.w = v.w - mean;
    float q = d.x * d.x + d.y * d.y + d.z * d.z + d.w * d.w;
    for (int o = 16; o > 0; o >>= 1) q += __shfl_down(q, o, 32);
    float inv = rsqrtf(__shfl(q, 0, 32) * (1.f / 128.f) + 1e-8f);
    const float4 gg = ((const float4*)g)[lane];
    const float4 bb = ((const float4*)b)[lane];
    float4 o4;
    o4.x = d.x * inv * gg.x + bb.x;
    o4.y = d.y * inv * gg.y + bb.y;
    o4.z = d.z * inv * gg.z + bb.z;
    o4.w = d.w * inv * gg.w + bb.w;
    ((float4*)(y + (size_t)row * TH))[lane] = o4;
}

// fused seq-mixing block; LDS transposed [l][8]/[s][8] for b128 broadcast reads
__global__ __launch_bounds__(256) void k_scb(const float* __restrict__ nv, float* __restrict__ vs,
                                             const float* __restrict__ w1, const float* __restrict__ w2) {
    __shared__ __align__(16) float nvc[TL][8];
    __shared__ __align__(16) float tt[TSH][8];
    int b = blockIdx.x >> 4;
    int h0 = (blockIdx.x & 15) * 8;
    int tid = threadIdx.x;
    for (int i = tid; i < TL * 8; i += 256) {
        int l = i >> 3, hh = i & 7;
        nvc[l][hh] = nv[(size_t)(b * TL + l) * TH + h0 + hh];
    }
    __syncthreads();
    {
        float a0[8], a1[8];
#pragma unroll
        for (int j = 0; j < 8; ++j) { a0[j] = 0.f; a1[j] = 0.f; }
        for (int l = 0; l < TL; ++l) {
            const float4 na = *(const float4*)&nvc[l][0];
            const float4 nb = *(const float4*)&nvc[l][4];
            float wa = w1[l * TSH + tid];
            float wb = w1[l * TSH + tid + 256];
            a0[0] += na.x * wa; a0[1] += na.y * wa; a0[2] += na.z * wa; a0[3] += na.w * wa;
            a0[4] += nb.x * wa; a0[5] += nb.y * wa; a0[6] += nb.z * wa; a0[7] += nb.w * wa;
            a1[0] += na.x * wb; a1[1] += na.y * wb; a1[2] += na.z * wb; a1[3] += na.w * wb;
            a1[4] += nb.x * wb; a1[5] += nb.y * wb; a1[6] += nb.z * wb; a1[7] += nb.w * wb;
        }
#pragma unroll
        for (int j = 0; j < 8; ++j) {
            tt[tid][j] = gelu_exact(a0[j]);
            tt[tid + 256][j] = gelu_exact(a1[j]);
        }
    }
    __syncthreads();
    if (tid < TL) {
        float acc[8];
#pragma unroll
        for (int j = 0; j < 8; ++j) acc[j] = nvc[tid][j];
        for (int s = 0; s < TSH; ++s) {
            const float4 ta = *(const float4*)&tt[s][0];
            const float4 tb = *(const float4*)&tt[s][4];
            float wl = w2[s * TL + tid];
            acc[0] += ta.x * wl; acc[1] += ta.y * wl; acc[2] += ta.z * wl; acc[3] += ta.w * wl;
            acc[4] += tb.x * wl; acc[5] += tb.y * wl; acc[6] += tb.z * wl; acc[7] += tb.w * wl;
        }
        float* vp = &vs[(size_t)(b * TL + tid) * TH + h0];
        float4 u0, u1;
        u0.x = acc[0]; u0.y = acc[1]; u0.z = acc[2]; u0.w = acc[3];
        u1.x = acc[4]; u1.y = acc[5]; u1.z = acc[6]; u1.w = acc[7];
        *(float4*)vp = u0;
        *(float4*)(vp + 4) = u1;
    }
}

// fused per-(b,l group of 4) feature block
__global__ __launch_bounds__(256) void k_fcb(const float* __restrict__ nvs, float* __restrict__ V,
                                             const float* __restrict__ w1, const float* __restrict__ w2,
                                             const float* __restrict__ w3) {
    __shared__ float xs[4][TH];
    __shared__ float ys[4][1024];
    __shared__ float zs[4][TH];
    int bl0 = blockIdx.x * 4;
    int tid = threadIdx.x;
    for (int i = tid; i < 4 * TH; i += 256) {
        int il = i >> 7, h = i & 127;
        xs[il][h] = nvs[(size_t)(bl0 + il) * TH + h];
    }
    __syncthreads();
    for (int i = tid; i < 4 * 1024; i += 256) {
        int il = i >> 10, kf = i & 1023, k = kf >> 8, f = kf & 255;
        float a = 0.f;
#pragma unroll
        for (int c = 0; c < TD; ++c) a += xs[il][k * TD + c] * w1[c * TFH + f];
        ys[il][kf] = gelu_exact(a);
    }
    __syncthreads();
    for (int i = tid; i < 4 * TH; i += 256) {
        int il = i >> 7, h = i & 127, k = h >> 5, c = h & 31;
        float a = 0.f;
        for (int f = 0; f < TFH; ++f) a += ys[il][k * TFH + f] * w2[f * TD + c];
        zs[il][h] = a;
    }
    __syncthreads();
    for (int i = tid; i < 4 * TH; i += 256) {
        int il = i >> 7, h = i & 127;
        float a = 0.f;
        for (int hp = 0; hp < TH; ++hp) a += zs[il][hp] * w3[hp * TH + h];
        V[(size_t)(bl0 + il) * TH + h] = xs[il][h] + a;
    }
}

// alpha = softmax(V@wv over L); g = sum_l alpha*V
__global__ __launch_bounds__(256) void k_pool(const float* __restrict__ V, const float* __restrict__ wv,
                                              float* __restrict__ g) {
    __shared__ float sc[TL];
    __shared__ float red[4];
    int b = blockIdx.x, tid = threadIdx.x;
    if (tid < TL) {
        float a = 0.f;
        const float* vp = V + (size_t)(b * TL + tid) * TH;
        for (int h = 0; h < TH; ++h) a += vp[h] * wv[h];
        sc[tid] = a;
    }
    __syncthreads();
    float m = (tid < TL) ? sc[tid] : -INFINITY;
    m = block_reduce_max(m, red);
    float e = (tid < TL) ? expf(sc[tid] - m) : 0.f;
    float s = block_reduce_sum(e, red);
    if (tid < TL) sc[tid] = e / s;
    __syncthreads();
    if (tid < TH) {
        float a = 0.f;
        for (int l = 0; l < TL; ++l) a += sc[l] * V[(size_t)(b * TL + l) * TH + tid];
        g[b * TH + tid] = a;
    }
}

// y[N,128] = x[N,128] @ W[128,128]; xs transposed for b128 broadcast
__global__ __launch_bounds__(256) void k_gemm128(const float* __restrict__ x, const float* __restrict__ W,
                                                 float* __restrict__ y, int nrows) {
    __shared__ __align__(16) float xs[TH][36];
    int row0 = blockIdx.x * 32;
    int tid = threadIdx.x;
    for (int i = tid; i < 32 * 32; i += 256) {
        int r = i >> 5, h4 = i & 31;
        int rr = row0 + r;
        float4 v;
        if (rr < nrows) v = ((const float4*)(x + (size_t)rr * TH))[h4];
        else { v.x = v.y = v.z = v.w = 0.f; }
        xs[h4 * 4 + 0][r] = v.x;
        xs[h4 * 4 + 1][r] = v.y;
        xs[h4 * 4 + 2][r] = v.z;
        xs[h4 * 4 + 3][r] = v.w;
    }
    __syncthreads();
    int c = tid & 127, rg = tid >> 7;
    float acc[16];
#pragma unroll
    for (int i = 0; i < 16; ++i) acc[i] = 0.f;
    for (int h = 0; h < TH; ++h) {
        float wv = W[h * TH + c];
        const float4 x0 = *(const float4*)&xs[h][rg * 16 + 0];
        const float4 x1 = *(const float4*)&xs[h][rg * 16 + 4];
        const float4 x2 = *(const float4*)&xs[h][rg * 16 + 8];
        const float4 x3 = *(const float4*)&xs[h][rg * 16 + 12];
        acc[0] += x0.x * wv;  acc[1] += x0.y * wv;  acc[2] += x0.z * wv;  acc[3] += x0.w * wv;
        acc[4] += x1.x * wv;  acc[5] += x1.y * wv;  acc[6] += x1.z * wv;  acc[7] += x1.w * wv;
        acc[8] += x2.x * wv;  acc[9] += x2.y * wv;  acc[10] += x2.z * wv; acc[11] += x2.w * wv;
        acc[12] += x3.x * wv; acc[13] += x3.y * wv; acc[14] += x3.z * wv; acc[15] += x3.w * wv;
    }
#pragma unroll
    for (int i = 0; i < 16; ++i) {
        int rr = row0 + rg * 16 + i;
        if (rr < nrows) y[(size_t)rr * TH + c] = acc[i];
    }
}

// out[n,k] = sum_d f[n, k*32+d] * vec[k*32+d]
__global__ __launch_bounds__(256) void k_scores(const float* __restrict__ f, const float* __restrict__ vec,
                                                float* __restrict__ out, int n) {
    int idx = blockIdx.x * blockDim.x + threadIdx.x;
    if (idx >= n * TNH) return;
    int node = idx >> 2, k = idx & 3;
    const float* fp = f + (size_t)node * TH + k * TD;
    const float* vp = vec + k * TD;
    float a = 0.f;
#pragma unroll
    for (int d = 0; d < TD; ++d) a += fp[d] * vp[d];
    out[idx] = a;
}

// fused per-dst-node GAT for both graphs
__global__ __launch_bounds__(128) void k_gat(const float* __restrict__ tax_cur,
                                             const float* __restrict__ fs_i, const float* __restrict__ el_i,
                                             const float* __restrict__ er_i, const int* __restrict__ src_i,
                                             const float* __restrict__ bi,
                                             const float* __restrict__ fs_t, const float* __restrict__ el_t,
                                             const float* __restrict__ er_t, const int* __restrict__ src_t,
                                             const float* __restrict__ bt,
                                             float* __restrict__ tax_nxt, float* __restrict__ acc, int hop) {
    int n = blockIdx.x, h = threadIdx.x, k = h >> 5;
    float cur = tax_cur[(size_t)n * TH + h];
    float ti, tt2;
    {
        float er = er_i[n * 4 + k];
        int s[4]; float e[4]; float m = -INFINITY;
#pragma unroll
        for (int j = 0; j < 4; ++j) {
            s[j] = src_i[n * 4 + j];
            float xx = el_i[s[j] * 4 + k] + er;
            e[j] = xx > 0.f ? xx : 0.2f * xx;
            m = fmaxf(m, e[j]);
        }
        float ssum = 0.f, av = 0.f;
#pragma unroll
        for (int j = 0; j < 4; ++j) {
            float a = expf(e[j] - m);
            ssum += a;
            av += a * fs_i[(size_t)s[j] * TH + h];
        }
        ti = fmaxf(av / ssum + cur + bi[h], 0.f);
    }
    {
        float er = er_t[n * 4 + k];
        int s[2]; float e[2]; float m = -INFINITY;
#pragma unroll
        for (int j = 0; j < 2; ++j) {
            s[j] = src_t[n * 2 + j];
            float xx = el_t[s[j] * 4 + k] + er;
            e[j] = xx > 0.f ? xx : 0.2f * xx;
            m = fmaxf(m, e[j]);
        }
        float ssum = 0.f, av = 0.f;
#pragma unroll
        for (int j = 0; j < 2; ++j) {
            float a = expf(e[j] - m);
            ssum += a;
            av += a * fs_t[(size_t)s[j] * TH + h];
        }
        tt2 = fmaxf(av / ssum + cur + bt[h], 0.f);
    }
    float nx = ti + tt2;
    size_t ai = (size_t)n * TH + h;
    tax_nxt[ai] = nx;
    acc[ai] = (hop == 0) ? nx : acc[ai] + nx;
}

// local + mul
__global__ __launch_bounds__(128) void k_local(const int* __restrict__ root, const float* __restrict__ acc,
                                               const float* __restrict__ g, float* __restrict__ local,
                                               float* __restrict__ mul) {
    __shared__ float red[2];
    int bf = blockIdx.x, b = bf >> 5;
    int h = threadIdx.x;
    int r = root[bf];
    float v = 0.f;
    if (r != -1) {
        int rc = r < 0 ? 0 : r;
        v = acc[(size_t)(b * TTP + rc) * TH + h] * 0.5f;
    }
    local[(size_t)bf * TH + h] = v;
    float s = block_reduce_sum(v * g[b * TH + h], red);
    if (h == 0) mul[bf] = s;
}

// per-b fuse; writes PT[h][b] (transposed p) for k_final
__global__ __launch_bounds__(128) void k_fuse(const float* __restrict__ mul, const float* __restrict__ local,
                                              const float* __restrict__ g,
                                              const float* __restrict__ liw_g, const float* __restrict__ liw_b,
                                              const float* __restrict__ int_g, const float* __restrict__ int_b,
                                              const float* __restrict__ uni_w, float* __restrict__ PT) {
    __shared__ float lm[TFT], wv_[TFT], inten[TH];
    __shared__ float red[2];
    int b = blockIdx.x, tid = threadIdx.x;
    if (tid < TFT) lm[tid] = mul[b * TFT + tid];
    __syncthreads();
    if (tid < TFT) {
        float mean = 0.f;
        for (int f = 0; f < TFT; ++f) mean += lm[f];
        mean *= (1.f / TFT);
        float var = 0.f;
        for (int f = 0; f < TFT; ++f) { float d = lm[f] - mean; var += d * d; }
        var *= (1.f / TFT);
        float ln = (lm[tid] - mean) * rsqrtf(var + 1e-8f) * liw_g[tid] + liw_b[tid];
        wv_[tid] = (lm[tid] != 0.f) ? ln : -INFINITY;
    }
    __syncthreads();
    if (tid < TFT) {
        float mx = -INFINITY;
        for (int f = 0; f < TFT; ++f) mx = fmaxf(mx, wv_[f]);
        float s = 0.f;
        for (int f = 0; f < TFT; ++f) s += expf(wv_[f] - mx);
        lm[tid] = expf(wv_[tid] - mx) / s;
    }
    __syncthreads();
    float ip = g[b * TH + tid];
    for (int f = 0; f < TFT; ++f) ip += lm[f] * local[(size_t)(b * TFT + f) * TH + tid];
    float mean = block_reduce_sum(ip, red) * (1.f / TH);
    float d = ip - mean;
    float var = block_reduce_sum(d * d, red) * (1.f / TH);
    inten[tid] = d * rsqrtf(var + 1e-8f) * int_g[tid] + int_b[tid];
    __syncthreads();
    float a = 0.f;
    for (int hp = 0; hp < TH; ++hp) a += inten[hp] * uni_w[hp * TH + tid];
    PT[tid * TB + b] = a;   // transposed store
}

// out[b,i] = dot(PT[:,b], E[i,:]); 64-item block, E staged once, full batch swept
__global__ __launch_bounds__(256) void k_final(const float* __restrict__ PT, const float* __restrict__ E,
                                               float* __restrict__ out) {
    __shared__ float es[64][129];
    int i0 = blockIdx.x * 64;
    int tid = threadIdx.x;
    for (int i = tid; i < 64 * 32; i += 256) {
        int ii = i >> 5, h4 = i & 31;
        int it = i0 + ii;
        float4 v;
        if (it < TITEMS) v = ((const float4*)(E + (size_t)it * TH))[h4];
        else { v.x = v.y = v.z = v.w = 0.f; }
        es[ii][h4 * 4 + 0] = v.x;
        es[ii][h4 * 4 + 1] = v.y;
        es[ii][h4 * 4 + 2] = v.z;
        es[ii][h4 * 4 + 3] = v.w;
    }
    __syncthreads();
    int iq = tid & 15, bq = tid >> 4;
#pragma unroll 1
    for (int sweep = 0; sweep < 4; ++sweep) {
        int bb = sweep * 128 + bq * 8;
        float acc[8][4];
#pragma unroll
        for (int j = 0; j < 8; ++j)
#pragma unroll
            for (int t = 0; t < 4; ++t) acc[j][t] = 0.f;
        for (int h = 0; h < TH; ++h) {
            const float4 pA = *(const float4*)(PT + h * TB + bb);
            const float4 pB = *(const float4*)(PT + h * TB + bb + 4);
            float ev[4];
            ev[0] = es[iq][h];
            ev[1] = es[iq + 16][h];
            ev[2] = es[iq + 32][h];
            ev[3] = es[iq + 48][h];
            float pv[8] = {pA.x, pA.y, pA.z, pA.w, pB.x, pB.y, pB.z, pB.w};
#pragma unroll
            for (int j = 0; j < 8; ++j)
#pragma unroll
                for (int t = 0; t < 4; ++t) acc[j][t] += pv[j] * ev[t];
        }
#pragma unroll
        for (int t = 0; t < 4; ++t) {
            int it = i0 + 16 * t + iq;
            if (it < TITEMS) {
#pragma unroll
                for (int j = 0; j < 8; ++j)
                    out[(size_t)(bb + j) * TITEMS + it] = acc[j][t];
            }
        }
    }
}

extern "C" void kernel_launch(void* const* d_in, const int* in_sizes, int n_in,
                              void* d_out, int out_size, void* d_ws, size_t ws_size,
                              hipStream_t stream) {
    const int*   seq        = (const int*)d_in[0];
    const int*   root       = (const int*)d_in[1];
    const int*   i2t_src    = (const int*)d_in[3];
    const int*   t2t_src    = (const int*)d_in[5];
    const int*   item_ids   = (const int*)d_in[6];
    const int*   tax_ids    = (const int*)d_in[7];
    const float* item_embed = (const float*)d_in[8];
    const float* tax_embed  = (const float*)d_in[9];
    const float* scb_ln_g   = (const float*)d_in[10];
    const float* scb_ln_b   = (const float*)d_in[11];
    const float* scb_w1     = (const float*)d_in[12];
    const float* scb_w2     = (const float*)d_in[13];
    const float* fcb_ln_g   = (const float*)d_in[14];
    const float* fcb_ln_b   = (const float*)d_in[15];
    const float* fcb_w1     = (const float*)d_in[16];
    const float* fcb_w2     = (const float*)d_in[17];
    const float* fcb_w3     = (const float*)d_in[18];
    const float* wv         = (const float*)d_in[19];
    const float* gi_w       = (const float*)d_in[20];
    const float* gi_al      = (const float*)d_in[21];
    const float* gi_ar      = (const float*)d_in[22];
    const float* gi_b       = (const float*)d_in[23];
    const float* gt_w       = (const float*)d_in[24];
    const float* gt_al      = (const float*)d_in[25];
    const float* gt_ar      = (const float*)d_in[26];
    const float* gt_b       = (const float*)d_in[27];
    const float* liw_g      = (const float*)d_in[28];
    const float* liw_b      = (const float*)d_in[29];
    const float* int_g      = (const float*)d_in[30];
    const float* int_b      = (const float*)d_in[31];
    const float* uni_w      = (const float*)d_in[32];

    char* w = (char*)d_ws;
    float* V     = (float*)(w + 0);           // region A: V / fs_i
    float* NV    = (float*)(w + 52428800);    // region B: nv / item_h
    float* FSI   = V;
    float* ITEMH = NV;
    float* TAX0  = (float*)(w + 104857600);
    float* TAX1  = (float*)(w + 121634816);
    float* ACC   = (float*)(w + 138412032);
    float* FDI   = (float*)(w + 155189248);   // dead after GAT -> reused as PT
    float* FST   = (float*)(w + 171966464);
    float* ELI   = (float*)(w + 188743680);
    float* ERI   = (float*)(w + 190382080);
    float* ELT   = (float*)(w + 190906368);
    float* ERT   = (float*)(w + 191430656);
    float* LOCAL = (float*)(w + 191954944);
    float* G     = (float*)(w + 200343552);
    float* MUL   = (float*)(w + 200605696);
    float* PT    = FDI;                       // [TH][TB] = 256 KB, aliases FDI
    if (ws_size < 200933376ull) return;

    // ---- global intention (mixer) ----
    k_gather<<<(TB * TL * 32 + 255) / 256, 256, 0, stream>>>(item_embed, seq, V, TB * TL);
    for (int nb = 0; nb < 2; ++nb) {
        k_ln<<<TB * TL / 8, 256, 0, stream>>>(V, NV, scb_ln_g + nb * TH, scb_ln_b + nb * TH);
        k_scb<<<TB * 16, 256, 0, stream>>>(NV, V, scb_w1 + nb * TL * TSH, scb_w2 + nb * TSH * TL);
        k_ln<<<TB * TL / 8, 256, 0, stream>>>(V, NV, fcb_ln_g + nb * TH, fcb_ln_b + nb * TH);
        k_fcb<<<TB * TL / 4, 256, 0, stream>>>(NV, V, fcb_w1 + nb * TD * TFH,
                                               fcb_w2 + nb * TFH * TD, fcb_w3 + nb * TH * TH);
    }
    k_pool<<<TB, 256, 0, stream>>>(V, wv, G);

    // ---- local intention (GAT) ----
    k_gather<<<(TNI * 32 + 255) / 256, 256, 0, stream>>>(item_embed, item_ids, ITEMH, TNI);
    k_gather<<<(TNT * 32 + 255) / 256, 256, 0, stream>>>(tax_embed, tax_ids, TAX0, TNT);

    float* cur = TAX0;
    float* nxt = TAX1;
    for (int hop = 0; hop < 2; ++hop) {
        const float* Wi = gi_w + hop * TH * TH;
        const float* Wt = gt_w + hop * TH * TH;
        k_gemm128<<<(TNI + 31) / 32, 256, 0, stream>>>(ITEMH, Wi, FSI, TNI);
        k_gemm128<<<(TNT + 31) / 32, 256, 0, stream>>>(cur, Wi, FDI, TNT);
        k_gemm128<<<(TNT + 31) / 32, 256, 0, stream>>>(cur, Wt, FST, TNT);
        k_scores<<<(TNI * TNH + 255) / 256, 256, 0, stream>>>(FSI, gi_al + hop * TH, ELI, TNI);
        k_scores<<<(TNT * TNH + 255) / 256, 256, 0, stream>>>(FDI, gi_ar + hop * TH, ERI, TNT);
        k_scores<<<(TNT * TNH + 255) / 256, 256, 0, stream>>>(FST, gt_al + hop * TH, ELT, TNT);
        k_scores<<<(TNT * TNH + 255) / 256, 256, 0, stream>>>(FST, gt_ar + hop * TH, ERT, TNT);
        k_gat<<<TNT, 128, 0, stream>>>(cur, FSI, ELI, ERI, i2t_src, gi_b + hop * TH,
                                       FST, ELT, ERT, t2t_src, gt_b + hop * TH, nxt, ACC, hop);
        float* tmp = cur; cur = nxt; nxt = tmp;
    }

    // ---- fuse ----
    k_local<<<TB * TFT, 128, 0, stream>>>(root, ACC, G, LOCAL, MUL);
    k_fuse<<<TB, 128, 0, stream>>>(MUL, LOCAL, G, liw_g, liw_b, int_g, int_b, uni_w, PT);

    k_final<<<(TITEMS + 63) / 64, 256, 0, stream>>>(PT, item_embed, (float*)d_out);
}